// Round 11
// baseline (279.590 us; speedup 1.0000x reference)
//
#include <hip/hip_runtime.h>
#include <hip/hip_bf16.h>

#define NROW 8192
#define NF   128
#define LOG2E 1.4426950408889634f

typedef float f32x4  __attribute__((ext_vector_type(4)));
typedef int   i32x4  __attribute__((ext_vector_type(4)));
typedef short bf16x8 __attribute__((ext_vector_type(8)));
typedef short bf16x4 __attribute__((ext_vector_type(4)));
typedef unsigned long long u64;

__device__ __forceinline__ short f2bf(float f) {
    union { float f; unsigned u; } v; v.f = f;
    unsigned r = v.u + 0x7FFFu + ((v.u >> 16) & 1u);
    return (short)(r >> 16);
}

// Tiled B layout: element (f, r) ->
//   (r>>6)*8192 + (f>>4)*1024 + ((r>>5)&1)*512 + (f&15)*32 + ((r>>3)&3)*8 + (r&7)

// k0: WT[c][k] = bf16(W[k][c])   (128x128, tiny)
__global__ __launch_bounds__(256) void k0_wt(const float* __restrict__ W,
                                             short* __restrict__ WT) {
    int idx = blockIdx.x * 256 + threadIdx.x;
    int c = idx >> 7, k = idx & 127;
    WT[c * NF + k] = f2bf(W[k * NF + c]);
}

// k1: Wh = mo @ W via bf16 MFMA -> tiled WhT, s1 = Wh@a1, s2 = Wh@a2.
__global__ __launch_bounds__(256) void k1_wh(const float* __restrict__ mo,
        const short* __restrict__ WT,
        const float* __restrict__ a1, const float* __restrict__ a2,
        short* __restrict__ WhT, float* __restrict__ s1g, float* __restrict__ s2g) {
    __shared__ float s_lds[2][32];
    int t = threadIdx.x;
    int w = t >> 6, l = t & 63, lg = l >> 4, lr = l & 15;
    int rows0 = blockIdx.x * 32;
    if (t < 64) s_lds[t >> 5][t & 31] = 0.0f;
    __syncthreads();

    f32x4 acc[2][2] = {};
#pragma unroll
    for (int ks = 0; ks < 4; ++ks) {
        bf16x8 a[2], b[2];
#pragma unroll
        for (int rt = 0; rt < 2; ++rt) {
            const float* ap = mo + (size_t)(rows0 + rt*16 + lr) * NF + ks*32 + lg*8;
            f32x4 x0 = *(const f32x4*)ap;
            f32x4 x1 = *(const f32x4*)(ap + 4);
#pragma unroll
            for (int e = 0; e < 4; ++e) { a[rt][e] = f2bf(x0[e]); a[rt][4+e] = f2bf(x1[e]); }
        }
#pragma unroll
        for (int ct = 0; ct < 2; ++ct) {
            int c = w*32 + ct*16 + lr;
            b[ct] = *(const bf16x8*)(WT + c*NF + ks*32 + lg*8);
        }
#pragma unroll
        for (int rt = 0; rt < 2; ++rt)
#pragma unroll
            for (int ct = 0; ct < 2; ++ct)
                acc[rt][ct] = __builtin_amdgcn_mfma_f32_16x16x32_bf16(a[rt], b[ct], acc[rt][ct], 0, 0, 0);
    }

    // C/D layout: col = lane&15, row = (lane>>4)*4 + reg
#pragma unroll
    for (int rt = 0; rt < 2; ++rt) {
        float p1[4] = {0,0,0,0}, p2[4] = {0,0,0,0};
#pragma unroll
        for (int ct = 0; ct < 2; ++ct) {
            int c = w*32 + ct*16 + lr;
            float a1c = a1[c], a2c = a2[c];
            bf16x4 wv;
#pragma unroll
            for (int g = 0; g < 4; ++g) {
                float v = acc[rt][ct][g];
                wv[g] = f2bf(v);
                p1[g] += v * a1c;
                p2[g] += v * a2c;
            }
            int r0 = rows0 + rt*16 + lg*4;
            size_t off = (size_t)(r0 >> 6) * 8192 + (size_t)(c >> 4) * 1024
                       + (size_t)((r0 >> 5) & 1) * 512 + (size_t)(c & 15) * 32
                       + (size_t)((r0 >> 3) & 3) * 8 + (size_t)(r0 & 7);
            *(bf16x4*)(WhT + off) = wv;
        }
#pragma unroll
        for (int off = 1; off < 16; off <<= 1) {
#pragma unroll
            for (int g = 0; g < 4; ++g) {
                p1[g] += __shfl_xor(p1[g], off);
                p2[g] += __shfl_xor(p2[g], off);
            }
        }
        if (lr == 0) {
            int rloc = rt*16 + lg*4;
#pragma unroll
            for (int g = 0; g < 4; ++g) {
                atomicAdd(&s_lds[0][rloc+g], p1[g]);
                atomicAdd(&s_lds[1][rloc+g], p2[g]);
            }
        }
    }
    __syncthreads();
    if (t < 32)       s1g[rows0 + t]        = s_lds[0][t];
    else if (t < 64)  s2g[rows0 + (t - 32)] = s_lds[1][t - 32];
}

// k2: block = 4 waves on SAME 16 rows, in-block j-split x4, cross-block x S.
// Counted-vmcnt register pipeline: vmem batches alternate Bv(16) | An(16);
// ballot waits only the old An batch, MFMA waits only the old Bv batch -> adj
// HBM latency gets a full iteration of cover, B gets exp-phase cover.
// exp2-domain LeakyReLU (log2e folded into s1/s2), packed bf16 conversion.
__global__ __launch_bounds__(256, 4) void k2_main(
        const int* __restrict__ adj, const short* __restrict__ WhT,
        const float* __restrict__ s1g, const float* __restrict__ s2g,
        float* __restrict__ numP, float* __restrict__ zP,
        int S, int npb) {
    __shared__ __attribute__((aligned(16))) char smem[16448];
    float* Lacc = (float*)smem;              // [2][2048] used after barrier
    float* s2l  = (float*)smem;              // [npb<=2048] during loop (alias)
    float* Lz   = (float*)(smem + 16384);    // [16]

    int t = threadIdx.x, w = t >> 6, l = t & 63;
    int lo = l & 15, hi = l >> 4;
    int b = blockIdx.x, jseg = b % S, rg = b / S;
    int rows0 = rg << 4;
    int j0 = jseg * npb;

    for (int i = t; i < (npb >> 2); i += 256) {
        f32x4 v = ((const f32x4*)(s2g + j0))[i];
        v *= LOG2E;
        ((f32x4*)s2l)[i] = v;
    }
    if (t < 16) Lz[t] = 0.0f;
    __syncthreads();

    int nwt = npb >> 2;
    int jb  = j0 + w * nwt;
    int NT  = nwt >> 6;

    float s1v = s1g[rows0 + lo] * LOG2E;
    const int* arow = adj + (size_t)rows0 * NROW + jb + l;

    f32x4 acc[8] = {};
    float z = 0.0f;

    int An[16];
    u64 bmq = 0;
    // prologue: tile 0 masks, tile 1 adj in flight
#pragma unroll
    for (int r = 0; r < 16; ++r) An[r] = arow[r * NROW];
#pragma unroll
    for (int r = 0; r < 16; ++r) {
        u64 br = __ballot(An[r] > 0);
        bmq = (lo == r) ? br : bmq;
    }
    {
        int j1 = (NT > 1) ? 1 : 0;
#pragma unroll
        for (int r = 0; r < 16; ++r) An[r] = arow[r * NROW + (j1 << 6)];
    }

    for (int it = 0; it < NT; ++it) {
        int jt = jb + (it << 6);
        // --- (1) Bv batch (16 x 1KB coalesced, L2) ---
        bf16x8 Bv[8][2];
        const short* tb = WhT + (size_t)(jt >> 6) * 8192 + lo*32 + hi*8;
#pragma unroll
        for (int ct = 0; ct < 8; ++ct) {
            Bv[ct][0] = *(const bf16x8*)(tb + ct*1024);
            Bv[ct][1] = *(const bf16x8*)(tb + ct*1024 + 512);
        }
        // --- (2) exp/mask from bmq (no memory wait) ---
        unsigned blo = (unsigned)(bmq >> (hi * 8)) & 0xffu;
        unsigned bhi = (unsigned)(bmq >> (32 + hi * 8)) & 0xffu;
        int jl = jt - j0;
        float pv[16];
        {
            f32x4 sa = *(const f32x4*)(s2l + jl + hi*8);
            f32x4 sb = *(const f32x4*)(s2l + jl + hi*8 + 4);
            f32x4 sc = *(const f32x4*)(s2l + jl + 32 + hi*8);
            f32x4 sd = *(const f32x4*)(s2l + jl + 32 + hi*8 + 4);
#pragma unroll
            for (int e = 0; e < 4; ++e) {
                float x, p;
                x = s1v + sa[e]; p = exp2f(fmaxf(x, 0.2f * x));
                p = ((blo >> e) & 1) ? p : 0.0f;       z += p; pv[e]      = p;
                x = s1v + sb[e]; p = exp2f(fmaxf(x, 0.2f * x));
                p = ((blo >> (4+e)) & 1) ? p : 0.0f;   z += p; pv[4+e]    = p;
                x = s1v + sc[e]; p = exp2f(fmaxf(x, 0.2f * x));
                p = ((bhi >> e) & 1) ? p : 0.0f;       z += p; pv[8+e]    = p;
                x = s1v + sd[e]; p = exp2f(fmaxf(x, 0.2f * x));
                p = ((bhi >> (4+e)) & 1) ? p : 0.0f;   z += p; pv[12+e]   = p;
            }
        }
        union { bf16x8 v8; __hip_bfloat162 h2[4]; } fa0u, fa1u;
#pragma unroll
        for (int q = 0; q < 4; ++q) {
            fa0u.h2[q] = __float22bfloat162_rn(make_float2(pv[2*q],     pv[2*q + 1]));
            fa1u.h2[q] = __float22bfloat162_rn(make_float2(pv[8 + 2*q], pv[8 + 2*q + 1]));
        }
        // --- (3) ballot for tile it+1 (waits An batch only, Bv stays in flight)
        // --- (4) issue An batch for tile it+2 ---
        if (it + 1 < NT) {
            u64 bmq2 = 0;
#pragma unroll
            for (int r = 0; r < 16; ++r) {
                u64 br = __ballot(An[r] > 0);
                bmq2 = (lo == r) ? br : bmq2;
            }
            int jn2 = (it + 2 < NT) ? (it + 2) : (NT - 1);
#pragma unroll
            for (int r = 0; r < 16; ++r) An[r] = arow[r * NROW + (jn2 << 6)];
            bmq = bmq2;
        }
        // --- (5) MFMA (waits Bv batch only, An stays in flight) ---
#pragma unroll
        for (int ct = 0; ct < 8; ++ct) {
            acc[ct] = __builtin_amdgcn_mfma_f32_16x16x32_bf16(fa0u.v8, Bv[ct][0], acc[ct], 0, 0, 0);
            acc[ct] = __builtin_amdgcn_mfma_f32_16x16x32_bf16(fa1u.v8, Bv[ct][1], acc[ct], 0, 0, 0);
        }
    }

    // --- z: lane's partial is for row lo; reduce across the 4 hi-groups ---
    z += __shfl_xor(z, 16);
    z += __shfl_xor(z, 32);
    if (l < 16) atomicAdd(&Lz[lo], z);
    __syncthreads();   // all waves done with s2l before Lacc writes (alias!)
    if (t < 16) zP[(size_t)jseg * NROW + rows0 + t] = Lz[t];

    // --- acc: tree-reduce 4 waves (identical (lane,ct,g)->(row,col) maps) ---
    if (w >= 2) {
        float* s0 = &Lacc[(w - 2) * 2048];
#pragma unroll
        for (int ct = 0; ct < 8; ++ct) *(f32x4*)(s0 + ct*256 + l*4) = acc[ct];
    }
    __syncthreads();
    if (w < 2) {
        const float* s0 = &Lacc[w * 2048];
#pragma unroll
        for (int ct = 0; ct < 8; ++ct) acc[ct] += *(const f32x4*)(s0 + ct*256 + l*4);
    }
    __syncthreads();
    if (w == 1) {
        float* s0 = &Lacc[0];
#pragma unroll
        for (int ct = 0; ct < 8; ++ct) *(f32x4*)(s0 + ct*256 + l*4) = acc[ct];
    }
    __syncthreads();
    if (w == 0) {
        const float* s0 = &Lacc[0];
        size_t obase = (size_t)jseg * NROW * NF;
#pragma unroll
        for (int ct = 0; ct < 8; ++ct) {
            acc[ct] += *(const f32x4*)(s0 + ct*256 + l*4);
            int cc = ct*16 + lo;
            int r0 = rows0 + hi*4;
#pragma unroll
            for (int g = 0; g < 4; ++g)
                numP[obase + (size_t)(r0 + g) * NF + cc] = acc[ct][g];
        }
    }
}

// k3: out = elu( sum_s num / sum_s z ), vectorized x4
__global__ __launch_bounds__(256) void k3_reduce(const float* __restrict__ numP,
        const float* __restrict__ zP, float* __restrict__ out, int S) {
    int idx = (blockIdx.x * 256 + threadIdx.x) * 4;
    int r = idx >> 7;
    f32x4 num = {};
    float zz = 0.0f;
    for (int s = 0; s < S; ++s) {
        f32x4 v = *(const f32x4*)(numP + (size_t)s * (NROW * NF) + idx);
        num += v;
        zz  += zP[s * NROW + r];
    }
    f32x4 o;
#pragma unroll
    for (int e = 0; e < 4; ++e) {
        float h = num[e] / zz;
        o[e] = (h > 0.0f) ? h : expm1f(h);
    }
    *(f32x4*)(out + idx) = o;
}

extern "C" void kernel_launch(void* const* d_in, const int* in_sizes, int n_in,
                              void* d_out, int out_size, void* d_ws, size_t ws_size,
                              hipStream_t stream) {
    const float* mo  = (const float*)d_in[0];
    const int*   adj = (const int*)d_in[1];
    const float* W   = (const float*)d_in[2];
    const float* a1  = (const float*)d_in[3];
    const float* a2  = (const float*)d_in[4];
    float* out = (float*)d_out;

    char* p = (char*)d_ws;
    short* WT  = (short*)p;  p += (size_t)NF * NF * 2;
    short* WhT = (short*)p;  p += (size_t)NF * NROW * 2;
    float* s1  = (float*)p;  p += (size_t)NROW * 4;
    float* s2  = (float*)p;  p += (size_t)NROW * 4;
    float* zP  = (float*)p;  p += (size_t)8 * NROW * 4;   // S<=8
    size_t fixed = (size_t)(p - (char*)d_ws);

    int S = 4;
    while (S > 1 && fixed + (size_t)S * NROW * NF * 4 > ws_size) S >>= 1;
    float* numP = (float*)p;
    if (fixed + (size_t)S * NROW * NF * 4 > ws_size) numP = out;  // S==1 fallback

    k0_wt<<<dim3(64), dim3(256), 0, stream>>>(W, WT);
    k1_wh<<<dim3(256), dim3(256), 0, stream>>>(mo, WT, a1, a2, WhT, s1, s2);
    k2_main<<<dim3((NROW / 16) * S), dim3(256), 0, stream>>>(adj, WhT, s1, s2, numP, zP, S, NROW / S);
    k3_reduce<<<dim3(NROW * NF / 1024), dim3(256), 0, stream>>>(numP, zP, out, S);
}

// Round 12
// 92.400 us; speedup vs baseline: 3.0259x; 3.0259x over previous
//
#include <hip/hip_runtime.h>
#include <hip/hip_bf16.h>

#define NROW 8192
#define NF   128
#define LOG2E 1.4426950408889634f

typedef float f32x4  __attribute__((ext_vector_type(4)));
typedef int   i32x4  __attribute__((ext_vector_type(4)));
typedef short bf16x8 __attribute__((ext_vector_type(8)));
typedef short bf16x4 __attribute__((ext_vector_type(4)));
typedef unsigned long long u64;

__device__ __forceinline__ short f2bf(float f) {
    union { float f; unsigned u; } v; v.f = f;
    unsigned r = v.u + 0x7FFFu + ((v.u >> 16) & 1u);
    return (short)(r >> 16);
}

__device__ __forceinline__ void gload_lds16(const short* g, short* l) {
    __builtin_amdgcn_global_load_lds(
        (const __attribute__((address_space(1))) void*)g,
        (__attribute__((address_space(3))) void*)l, 16, 0, 0);
}

// Tiled B layout (LDS-image order): element (f, j) ->
//   (j>>6)*8192 + (f>>4)*1024 + ((j>>5)&1)*512 + ((j>>3)&3)*128 + (f&15)*8 + (j&7)
// A fragment(ct,half) is 1KB with lane l's 16B at byte l*16 (conflict-free
// ds_read_b128 after a LINEAR global_load_lds copy).

// k0: WT[c][k] = bf16(W[k][c])
__global__ __launch_bounds__(256) void k0_wt(const float* __restrict__ W,
                                             short* __restrict__ WT) {
    int idx = blockIdx.x * 256 + threadIdx.x;
    int c = idx >> 7, k = idx & 127;
    WT[c * NF + k] = f2bf(W[k * NF + c]);
}

// k1: Wh = mo @ W via bf16 MFMA -> tiled WhT, s1/s2 = (Wh@a1, Wh@a2)*LOG2E.
__global__ __launch_bounds__(256) void k1_wh(const float* __restrict__ mo,
        const short* __restrict__ WT,
        const float* __restrict__ a1, const float* __restrict__ a2,
        short* __restrict__ WhT, float* __restrict__ s1g, float* __restrict__ s2g) {
    __shared__ float s_lds[2][32];
    int t = threadIdx.x;
    int w = t >> 6, l = t & 63, lg = l >> 4, lr = l & 15;
    int rows0 = blockIdx.x * 32;
    if (t < 64) s_lds[t >> 5][t & 31] = 0.0f;
    __syncthreads();

    f32x4 acc[2][2] = {};
#pragma unroll
    for (int ks = 0; ks < 4; ++ks) {
        bf16x8 a[2], b[2];
#pragma unroll
        for (int rt = 0; rt < 2; ++rt) {
            const float* ap = mo + (size_t)(rows0 + rt*16 + lr) * NF + ks*32 + lg*8;
            f32x4 x0 = *(const f32x4*)ap;
            f32x4 x1 = *(const f32x4*)(ap + 4);
#pragma unroll
            for (int e = 0; e < 4; ++e) { a[rt][e] = f2bf(x0[e]); a[rt][4+e] = f2bf(x1[e]); }
        }
#pragma unroll
        for (int ct = 0; ct < 2; ++ct) {
            int c = w*32 + ct*16 + lr;
            b[ct] = *(const bf16x8*)(WT + c*NF + ks*32 + lg*8);
        }
#pragma unroll
        for (int rt = 0; rt < 2; ++rt)
#pragma unroll
            for (int ct = 0; ct < 2; ++ct)
                acc[rt][ct] = __builtin_amdgcn_mfma_f32_16x16x32_bf16(a[rt], b[ct], acc[rt][ct], 0, 0, 0);
    }

    // C/D layout: col = lane&15, row = (lane>>4)*4 + reg
#pragma unroll
    for (int rt = 0; rt < 2; ++rt) {
        float p1[4] = {0,0,0,0}, p2[4] = {0,0,0,0};
#pragma unroll
        for (int ct = 0; ct < 2; ++ct) {
            int c = w*32 + ct*16 + lr;
            float a1c = a1[c], a2c = a2[c];
            bf16x4 wv;
#pragma unroll
            for (int g = 0; g < 4; ++g) {
                float v = acc[rt][ct][g];
                wv[g] = f2bf(v);
                p1[g] += v * a1c;
                p2[g] += v * a2c;
            }
            int r0 = rows0 + rt*16 + lg*4;   // multiple of 4
            size_t off = (size_t)(r0 >> 6) * 8192 + (size_t)(c >> 4) * 1024
                       + (size_t)((r0 >> 5) & 1) * 512 + (size_t)((r0 >> 3) & 3) * 128
                       + (size_t)(c & 15) * 8 + (size_t)(r0 & 7);
            *(bf16x4*)(WhT + off) = wv;
        }
#pragma unroll
        for (int off = 1; off < 16; off <<= 1) {
#pragma unroll
            for (int g = 0; g < 4; ++g) {
                p1[g] += __shfl_xor(p1[g], off);
                p2[g] += __shfl_xor(p2[g], off);
            }
        }
        if (lr == 0) {
            int rloc = rt*16 + lg*4;
#pragma unroll
            for (int g = 0; g < 4; ++g) {
                atomicAdd(&s_lds[0][rloc+g], p1[g]);
                atomicAdd(&s_lds[1][rloc+g], p2[g]);
            }
        }
    }
    __syncthreads();
    if (t < 32)       s1g[rows0 + t]        = s_lds[0][t] * LOG2E;
    else if (t < 64)  s2g[rows0 + (t - 32)] = s_lds[1][t - 32] * LOG2E;
}

// k2: block = 4 waves x 16 DISTINCT rows (64 rows/block), one j-segment.
// B tile (16KB) staged ONCE per block into LDS (global_load_lds, dbuf, one
// barrier/tile); B-L2 traffic drops 4x vs per-wave B loads. adj read once,
// coalesced, ballot-transposed. s2 in LDS -> no in-loop vmem consumer (the
// barrier's implicit vmcnt(0) is the only vmem wait, one tile of cover).
// Waves own disjoint rows -> direct zP/numP stores, no reduce, no atomics.
__global__ __launch_bounds__(256, 4) void k2_main(
        const int* __restrict__ adj, const short* __restrict__ WhT,
        const float* __restrict__ s1g, const float* __restrict__ s2g,
        float* __restrict__ numP, float* __restrict__ zP,
        int S, int npb) {
    __shared__ __attribute__((aligned(16))) short Bl[2][8192];  // 32 KB dbuf
    __shared__ __attribute__((aligned(16))) float s2l[2048];    // npb <= 2048

    int t = threadIdx.x, w = t >> 6, l = t & 63;
    int lo = l & 15, hi = l >> 4;
    int b = blockIdx.x, jseg = b % S, rg = b / S;
    int wrows0 = (rg << 6) + (w << 4);          // this wave's 16 rows
    int j0 = jseg * npb;
    int NT = npb >> 6;

    for (int i = t; i < (npb >> 2); i += 256)
        ((f32x4*)s2l)[i] = ((const f32x4*)(s2g + j0))[i];

    float s1v = s1g[wrows0 + lo];
    const int* arow = adj + (size_t)wrows0 * NROW + j0 + l;

    f32x4 acc[8] = {};
    float z = 0.0f;

    int An[16];
#pragma unroll
    for (int r = 0; r < 16; ++r) An[r] = arow[r * NROW];
    {   // stage tile 0 -> buf 0 (each wave stages its 4KB quarter)
        const short* gs = WhT + (size_t)(j0 >> 6) * 8192 + w*2048 + l*8;
        short* ds = &Bl[0][w*2048];
#pragma unroll
        for (int r4 = 0; r4 < 4; ++r4)
            gload_lds16(gs + r4*512, ds + r4*512);
    }

    int cur = 0;
    for (int it = 0; it < NT; ++it) {
        __syncthreads();   // An(it) + stage(it) complete; all done with buf[cur^1]
        // --- ballot-transpose: bmq = row lo's 64 mask bits; refill An(it+1) ---
        u64 bmq = 0;
        int more = (it + 1 < NT);
#pragma unroll
        for (int r = 0; r < 16; ++r) {
            u64 br = __ballot(An[r] > 0);
            if (more) An[r] = arow[r * NROW + ((it + 1) << 6)];
            bmq = (lo == r) ? br : bmq;
        }
        // --- stage tile it+1 into the other buffer (async, drained at next barrier)
        if (more) {
            const short* gs = WhT + (size_t)((j0 + ((it+1) << 6)) >> 6) * 8192 + w*2048 + l*8;
            short* ds = &Bl[cur ^ 1][w*2048];
#pragma unroll
            for (int r4 = 0; r4 < 4; ++r4)
                gload_lds16(gs + r4*512, ds + r4*512);
        }
        // --- exp/mask straight into A-fragments (s2 from LDS broadcast) ---
        int jt = it << 6;
        unsigned blo = (unsigned)(bmq >> (hi * 8)) & 0xffu;
        unsigned bhi = (unsigned)(bmq >> (32 + hi * 8)) & 0xffu;
        f32x4 sa = *(const f32x4*)(s2l + jt + hi*8);
        f32x4 sb = *(const f32x4*)(s2l + jt + hi*8 + 4);
        f32x4 sc = *(const f32x4*)(s2l + jt + 32 + hi*8);
        f32x4 sd = *(const f32x4*)(s2l + jt + 32 + hi*8 + 4);
        float p0[8], p1[8];
#pragma unroll
        for (int e = 0; e < 4; ++e) {
            float x, p;
            x = s1v + sa[e]; p = exp2f(fmaxf(x, 0.2f * x));
            p0[e]   = ((blo >> e) & 1) ? p : 0.0f;      z += p0[e];
            x = s1v + sb[e]; p = exp2f(fmaxf(x, 0.2f * x));
            p0[4+e] = ((blo >> (4+e)) & 1) ? p : 0.0f;  z += p0[4+e];
            x = s1v + sc[e]; p = exp2f(fmaxf(x, 0.2f * x));
            p1[e]   = ((bhi >> e) & 1) ? p : 0.0f;      z += p1[e];
            x = s1v + sd[e]; p = exp2f(fmaxf(x, 0.2f * x));
            p1[4+e] = ((bhi >> (4+e)) & 1) ? p : 0.0f;  z += p1[4+e];
        }
        union { bf16x8 v8; __hip_bfloat162 h2[4]; } fa0u, fa1u;
#pragma unroll
        for (int q = 0; q < 4; ++q) {
            fa0u.h2[q] = __float22bfloat162_rn(make_float2(p0[2*q], p0[2*q+1]));
            fa1u.h2[q] = __float22bfloat162_rn(make_float2(p1[2*q], p1[2*q+1]));
        }
        // --- MFMA from LDS buf[cur] (conflict-free ds_read_b128, lane-linear) ---
        const short* Bc = &Bl[cur][l * 8];
#pragma unroll
        for (int ct = 0; ct < 8; ++ct) {
            bf16x8 b0 = *(const bf16x8*)(Bc + ct*1024);
            bf16x8 b1 = *(const bf16x8*)(Bc + ct*1024 + 512);
            acc[ct] = __builtin_amdgcn_mfma_f32_16x16x32_bf16(fa0u.v8, b0, acc[ct], 0, 0, 0);
            acc[ct] = __builtin_amdgcn_mfma_f32_16x16x32_bf16(fa1u.v8, b1, acc[ct], 0, 0, 0);
        }
        cur ^= 1;
    }

    // --- epilogue: disjoint rows per wave -> direct stores, no reduction ---
    z += __shfl_xor(z, 16);
    z += __shfl_xor(z, 32);
    if (l < 16) zP[(size_t)jseg * NROW + wrows0 + lo] = z;

    size_t obase = (size_t)jseg * NROW * NF;
#pragma unroll
    for (int ct = 0; ct < 8; ++ct) {
        int cc = ct * 16 + lo;
        int r0 = wrows0 + hi * 4;
#pragma unroll
        for (int g = 0; g < 4; ++g)
            numP[obase + (size_t)(r0 + g) * NF + cc] = acc[ct][g];
    }
}

// k3: out = elu( sum_s num / sum_s z ), vectorized x4
__global__ __launch_bounds__(256) void k3_reduce(const float* __restrict__ numP,
        const float* __restrict__ zP, float* __restrict__ out, int S) {
    int idx = (blockIdx.x * 256 + threadIdx.x) * 4;
    int r = idx >> 7;
    f32x4 num = {};
    float zz = 0.0f;
    for (int s = 0; s < S; ++s) {
        f32x4 v = *(const f32x4*)(numP + (size_t)s * (NROW * NF) + idx);
        num += v;
        zz  += zP[s * NROW + r];
    }
    f32x4 o;
#pragma unroll
    for (int e = 0; e < 4; ++e) {
        float h = num[e] / zz;
        o[e] = (h > 0.0f) ? h : expm1f(h);
    }
    *(f32x4*)(out + idx) = o;
}

extern "C" void kernel_launch(void* const* d_in, const int* in_sizes, int n_in,
                              void* d_out, int out_size, void* d_ws, size_t ws_size,
                              hipStream_t stream) {
    const float* mo  = (const float*)d_in[0];
    const int*   adj = (const int*)d_in[1];
    const float* W   = (const float*)d_in[2];
    const float* a1  = (const float*)d_in[3];
    const float* a2  = (const float*)d_in[4];
    float* out = (float*)d_out;

    char* p = (char*)d_ws;
    short* WT  = (short*)p;  p += (size_t)NF * NF * 2;
    short* WhT = (short*)p;  p += (size_t)NF * NROW * 2;
    float* s1  = (float*)p;  p += (size_t)NROW * 4;
    float* s2  = (float*)p;  p += (size_t)NROW * 4;
    float* zP  = (float*)p;  p += (size_t)8 * NROW * 4;   // S<=8
    size_t fixed = (size_t)(p - (char*)d_ws);

    int S = 8;   // 128*8 = 1024 blocks = exactly 4 blocks/CU, all resident
    while (S > 1 && fixed + (size_t)S * NROW * NF * 4 > ws_size) S >>= 1;
    float* numP = (float*)p;
    if (fixed + (size_t)S * NROW * NF * 4 > ws_size) numP = out;  // S==1 fallback

    k0_wt<<<dim3(64), dim3(256), 0, stream>>>(W, WT);
    k1_wh<<<dim3(256), dim3(256), 0, stream>>>(mo, WT, a1, a2, WhT, s1, s2);
    k2_main<<<dim3((NROW / 64) * S), dim3(256), 0, stream>>>(adj, WhT, s1, s2, numP, zP, S, NROW / S);
    k3_reduce<<<dim3(NROW * NF / 1024), dim3(256), 0, stream>>>(numP, zP, out, S);
}

// Round 13
// 88.138 us; speedup vs baseline: 3.1722x; 1.0484x over previous
//
#include <hip/hip_runtime.h>
#include <hip/hip_bf16.h>

#define NROW 8192
#define NF   128
#define LOG2E 1.4426950408889634f

typedef float f32x4  __attribute__((ext_vector_type(4)));
typedef int   i32x4  __attribute__((ext_vector_type(4)));
typedef short bf16x8 __attribute__((ext_vector_type(8)));
typedef short bf16x4 __attribute__((ext_vector_type(4)));
typedef unsigned long long u64;

__device__ __forceinline__ short f2bf(float f) {
    union { float f; unsigned u; } v; v.f = f;
    unsigned r = v.u + 0x7FFFu + ((v.u >> 16) & 1u);
    return (short)(r >> 16);
}

__device__ __forceinline__ void gload_lds16(const short* g, short* l) {
    __builtin_amdgcn_global_load_lds(
        (const __attribute__((address_space(1))) void*)g,
        (__attribute__((address_space(3))) void*)l, 16, 0, 0);
}

// Tiled B layout (LDS-image order): element (f, j) ->
//   (j>>6)*8192 + (f>>4)*1024 + ((j>>5)&1)*512 + ((j>>3)&3)*128 + (f&15)*8 + (j&7)

// k0: WT[c][k] = bf16(W[k][c])
__global__ __launch_bounds__(256) void k0_wt(const float* __restrict__ W,
                                             short* __restrict__ WT) {
    int idx = blockIdx.x * 256 + threadIdx.x;
    int c = idx >> 7, k = idx & 127;
    WT[c * NF + k] = f2bf(W[k * NF + c]);
}

// k1: Wh = mo @ W via bf16 MFMA -> tiled WhT, s1/s2 = (Wh@a1, Wh@a2)*LOG2E.
__global__ __launch_bounds__(256) void k1_wh(const float* __restrict__ mo,
        const short* __restrict__ WT,
        const float* __restrict__ a1, const float* __restrict__ a2,
        short* __restrict__ WhT, float* __restrict__ s1g, float* __restrict__ s2g) {
    __shared__ float s_lds[2][32];
    int t = threadIdx.x;
    int w = t >> 6, l = t & 63, lg = l >> 4, lr = l & 15;
    int rows0 = blockIdx.x * 32;
    if (t < 64) s_lds[t >> 5][t & 31] = 0.0f;
    __syncthreads();

    f32x4 acc[2][2] = {};
#pragma unroll
    for (int ks = 0; ks < 4; ++ks) {
        bf16x8 a[2], b[2];
#pragma unroll
        for (int rt = 0; rt < 2; ++rt) {
            const float* ap = mo + (size_t)(rows0 + rt*16 + lr) * NF + ks*32 + lg*8;
            f32x4 x0 = *(const f32x4*)ap;
            f32x4 x1 = *(const f32x4*)(ap + 4);
#pragma unroll
            for (int e = 0; e < 4; ++e) { a[rt][e] = f2bf(x0[e]); a[rt][4+e] = f2bf(x1[e]); }
        }
#pragma unroll
        for (int ct = 0; ct < 2; ++ct) {
            int c = w*32 + ct*16 + lr;
            b[ct] = *(const bf16x8*)(WT + c*NF + ks*32 + lg*8);
        }
#pragma unroll
        for (int rt = 0; rt < 2; ++rt)
#pragma unroll
            for (int ct = 0; ct < 2; ++ct)
                acc[rt][ct] = __builtin_amdgcn_mfma_f32_16x16x32_bf16(a[rt], b[ct], acc[rt][ct], 0, 0, 0);
    }

    // C/D layout: col = lane&15, row = (lane>>4)*4 + reg
#pragma unroll
    for (int rt = 0; rt < 2; ++rt) {
        float p1[4] = {0,0,0,0}, p2[4] = {0,0,0,0};
#pragma unroll
        for (int ct = 0; ct < 2; ++ct) {
            int c = w*32 + ct*16 + lr;
            float a1c = a1[c], a2c = a2[c];
            bf16x4 wv;
#pragma unroll
            for (int g = 0; g < 4; ++g) {
                float v = acc[rt][ct][g];
                wv[g] = f2bf(v);
                p1[g] += v * a1c;
                p2[g] += v * a2c;
            }
            int r0 = rows0 + rt*16 + lg*4;   // multiple of 4
            size_t off = (size_t)(r0 >> 6) * 8192 + (size_t)(c >> 4) * 1024
                       + (size_t)((r0 >> 5) & 1) * 512 + (size_t)((r0 >> 3) & 3) * 128
                       + (size_t)(c & 15) * 8 + (size_t)(r0 & 7);
            *(bf16x4*)(WhT + off) = wv;
        }
#pragma unroll
        for (int off = 1; off < 16; off <<= 1) {
#pragma unroll
            for (int g = 0; g < 4; ++g) {
                p1[g] += __shfl_xor(p1[g], off);
                p2[g] += __shfl_xor(p2[g], off);
            }
        }
        if (lr == 0) {
            int rloc = rt*16 + lg*4;
#pragma unroll
            for (int g = 0; g < 4; ++g) {
                atomicAdd(&s_lds[0][rloc+g], p1[g]);
                atomicAdd(&s_lds[1][rloc+g], p2[g]);
            }
        }
    }
    __syncthreads();
    if (t < 32)       s1g[rows0 + t]        = s_lds[0][t] * LOG2E;
    else if (t < 64)  s2g[rows0 + (t - 32)] = s_lds[1][t - 32] * LOG2E;
}

// k2: block = 4 waves x 16 DISTINCT rows, one j-segment; 128-j tiles (NT=8).
// An batch = 32 loads (8KB/wave, 32KB/block burst >= its HBM service time ->
// high queue occupancy; fixes the 57% duty-cycle of 64-j tiles). B tile 32KB
// single-buffered in LDS (40KB total -> 4 blocks/CU), two barriers/iteration:
// [barrier: stage done] ballot+exp+MFMA [barrier: compute done] stage(it+1).
__global__ __launch_bounds__(256, 4) void k2_main(
        const int* __restrict__ adj, const short* __restrict__ WhT,
        const float* __restrict__ s1g, const float* __restrict__ s2g,
        float* __restrict__ numP, float* __restrict__ zP,
        int S, int npb) {
    __shared__ __attribute__((aligned(16))) short Bl[16384];  // 32KB: 2 images
    __shared__ __attribute__((aligned(16))) float s2l[2048];

    int t = threadIdx.x, w = t >> 6, l = t & 63;
    int lo = l & 15, hi = l >> 4;
    int b = blockIdx.x, jseg = b % S, rg = b / S;
    int wrows0 = (rg << 6) + (w << 4);          // this wave's 16 rows
    int j0 = jseg * npb;
    int NT = npb >> 7;                          // 128 j per iteration

    for (int i = t; i < (npb >> 2); i += 256)
        ((f32x4*)s2l)[i] = ((const f32x4*)(s2g + j0))[i];

    float s1v = s1g[wrows0 + lo];
    const int* arow = adj + (size_t)wrows0 * NROW + j0 + l;

    f32x4 acc[8] = {};
    float z = 0.0f;

    int An[32];
#pragma unroll
    for (int r = 0; r < 16; ++r) {
        An[r]      = arow[r * NROW];
        An[16 + r] = arow[r * NROW + 64];
    }
    {   // stage tile 0 (each wave stages its 8KB quarter of the 32KB tile)
        const short* gs = WhT + (size_t)(j0 >> 6) * 8192 + w*4096 + l*8;
        short* ds = &Bl[w*4096];
#pragma unroll
        for (int r8 = 0; r8 < 8; ++r8)
            gload_lds16(gs + r8*512, ds + r8*512);
    }
    __syncthreads();   // An(0) + stage(0) complete

    for (int it = 0; it < NT; ++it) {
        // --- ballot-transpose 16 rows x 128 j -> two u64 masks for row lo ---
        u64 bmqA = 0, bmqB = 0;
#pragma unroll
        for (int r = 0; r < 16; ++r) {
            u64 brA = __ballot(An[r] > 0);
            u64 brB = __ballot(An[16 + r] > 0);
            bmqA = (lo == r) ? brA : bmqA;
            bmqB = (lo == r) ? brB : bmqB;
        }
        int more = (it + 1 < NT);
        if (more) {   // refill An(it+1): 8KB burst, drains at the next barrier
            int joff = (it + 1) << 7;
#pragma unroll
            for (int r = 0; r < 16; ++r) {
                An[r]      = arow[r * NROW + joff];
                An[16 + r] = arow[r * NROW + joff + 64];
            }
        }
        // --- 4 K-slices of 32 j: exp/mask into A-frag, 8 MFMAs each ---
#pragma unroll
        for (int ks = 0; ks < 4; ++ks) {
            u64 bq = (ks < 2) ? bmqA : bmqB;
            unsigned bits = (unsigned)(bq >> (((ks & 1) << 5) + hi * 8)) & 0xffu;
            int js = (it << 7) + ks * 32 + hi * 8;
            f32x4 sa = *(const f32x4*)(s2l + js);
            f32x4 sb = *(const f32x4*)(s2l + js + 4);
            float p[8];
#pragma unroll
            for (int e = 0; e < 4; ++e) {
                float x, pe;
                x = s1v + sa[e]; pe = exp2f(fmaxf(x, 0.2f * x));
                p[e]     = ((bits >> e) & 1) ? pe : 0.0f;        z += p[e];
                x = s1v + sb[e]; pe = exp2f(fmaxf(x, 0.2f * x));
                p[4 + e] = ((bits >> (4 + e)) & 1) ? pe : 0.0f;  z += p[4 + e];
            }
            union { bf16x8 v8; __hip_bfloat162 h2[4]; } fau;
#pragma unroll
            for (int q = 0; q < 4; ++q)
                fau.h2[q] = __float22bfloat162_rn(make_float2(p[2*q], p[2*q + 1]));
            const short* Bc = &Bl[(ks >> 1) * 8192 + (ks & 1) * 512 + l * 8];
#pragma unroll
            for (int ct = 0; ct < 8; ++ct) {
                bf16x8 bv = *(const bf16x8*)(Bc + ct * 1024);
                acc[ct] = __builtin_amdgcn_mfma_f32_16x16x32_bf16(fau.v8, bv, acc[ct], 0, 0, 0);
            }
        }
        __syncthreads();   // all waves done reading Bl; An(it+1) drained (covered)
        if (more) {        // stage tile it+1 into Bl
            const short* gs = WhT + (size_t)((j0 + ((it + 1) << 7)) >> 6) * 8192 + w*4096 + l*8;
            short* ds = &Bl[w*4096];
#pragma unroll
            for (int r8 = 0; r8 < 8; ++r8)
                gload_lds16(gs + r8*512, ds + r8*512);
            __syncthreads();   // stage complete
        }
    }

    // --- epilogue: disjoint rows per wave -> direct stores, no reduction ---
    z += __shfl_xor(z, 16);
    z += __shfl_xor(z, 32);
    if (l < 16) zP[(size_t)jseg * NROW + wrows0 + lo] = z;

    size_t obase = (size_t)jseg * NROW * NF;
#pragma unroll
    for (int ct = 0; ct < 8; ++ct) {
        int cc = ct * 16 + lo;
        int r0 = wrows0 + hi * 4;
#pragma unroll
        for (int g = 0; g < 4; ++g)
            numP[obase + (size_t)(r0 + g) * NF + cc] = acc[ct][g];
    }
}

// k3: out = elu( sum_s num / sum_s z ), vectorized x4
__global__ __launch_bounds__(256) void k3_reduce(const float* __restrict__ numP,
        const float* __restrict__ zP, float* __restrict__ out, int S) {
    int idx = (blockIdx.x * 256 + threadIdx.x) * 4;
    int r = idx >> 7;
    f32x4 num = {};
    float zz = 0.0f;
    for (int s = 0; s < S; ++s) {
        f32x4 v = *(const f32x4*)(numP + (size_t)s * (NROW * NF) + idx);
        num += v;
        zz  += zP[s * NROW + r];
    }
    f32x4 o;
#pragma unroll
    for (int e = 0; e < 4; ++e) {
        float h = num[e] / zz;
        o[e] = (h > 0.0f) ? h : expm1f(h);
    }
    *(f32x4*)(out + idx) = o;
}

extern "C" void kernel_launch(void* const* d_in, const int* in_sizes, int n_in,
                              void* d_out, int out_size, void* d_ws, size_t ws_size,
                              hipStream_t stream) {
    const float* mo  = (const float*)d_in[0];
    const int*   adj = (const int*)d_in[1];
    const float* W   = (const float*)d_in[2];
    const float* a1  = (const float*)d_in[3];
    const float* a2  = (const float*)d_in[4];
    float* out = (float*)d_out;

    char* p = (char*)d_ws;
    short* WT  = (short*)p;  p += (size_t)NF * NF * 2;
    short* WhT = (short*)p;  p += (size_t)NF * NROW * 2;
    float* s1  = (float*)p;  p += (size_t)NROW * 4;
    float* s2  = (float*)p;  p += (size_t)NROW * 4;
    float* zP  = (float*)p;  p += (size_t)8 * NROW * 4;   // S<=8
    size_t fixed = (size_t)(p - (char*)d_ws);

    int S = 8;   // 128*8 = 1024 blocks = exactly 4 blocks/CU, npb=1024, NT=8
    while (S > 1 && fixed + (size_t)S * NROW * NF * 4 > ws_size) S >>= 1;
    float* numP = (float*)p;
    if (fixed + (size_t)S * NROW * NF * 4 > ws_size) numP = out;  // S==1 fallback

    k0_wt<<<dim3(64), dim3(256), 0, stream>>>(W, WT);
    k1_wh<<<dim3(256), dim3(256), 0, stream>>>(mo, WT, a1, a2, WhT, s1, s2);
    k2_main<<<dim3((NROW / 64) * S), dim3(256), 0, stream>>>(adj, WhT, s1, s2, numP, zP, S, NROW / S);
    k3_reduce<<<dim3(NROW * NF / 1024), dim3(256), 0, stream>>>(numP, zP, out, S);
}